// Round 8
// baseline (1146.376 us; speedup 1.0000x reference)
//
#include <hip/hip_runtime.h>
#include <stdint.h>
#include <math.h>

#define NN 50000          // nodes
#define NE 800000         // edges
#define NH 4              // heads

typedef __attribute__((ext_vector_type(8))) short short8;
typedef __attribute__((ext_vector_type(4))) float floatx4;

// ======================= bf16 helpers =======================
__device__ inline float bf2f(uint32_t u16)
{
    return __uint_as_float(u16 << 16);
}
__device__ inline uint16_t f2bf(float f)
{
    uint32_t u = __float_as_uint(f);
    uint32_t r = (u + 0x7fffu + ((u >> 16) & 1u)) >> 16;   // RNE
    return (uint16_t)r;
}
__device__ inline void unpk8(uint4 u, float* f)
{
    f[0] = bf2f(u.x & 0xffffu); f[1] = bf2f(u.x >> 16);
    f[2] = bf2f(u.y & 0xffffu); f[3] = bf2f(u.y >> 16);
    f[4] = bf2f(u.z & 0xffffu); f[5] = bf2f(u.z >> 16);
    f[6] = bf2f(u.w & 0xffffu); f[7] = bf2f(u.w >> 16);
}

// intra-wave LDS producer->consumer sync (single wave; no __syncthreads needed):
// drain this wave's outstanding LDS ops; wave_barrier pins scheduling.
__device__ inline void wave_lds_sync()
{
    __builtin_amdgcn_wave_barrier();
    asm volatile("s_waitcnt lgkmcnt(0)" ::: "memory");
    __builtin_amdgcn_wave_barrier();
}

// ======================= JAX threefry2x32 (partitionable mode) =======================
__host__ __device__ inline void tf2x32(uint32_t k0, uint32_t k1,
                                       uint32_t x0, uint32_t x1,
                                       uint32_t& o0, uint32_t& o1)
{
    uint32_t ks2 = k0 ^ k1 ^ 0x1BD11BDAu;
    x0 += k0; x1 += k1;
#define TF_R(r) { x0 += x1; x1 = (x1 << (r)) | (x1 >> (32 - (r))); x1 ^= x0; }
    TF_R(13) TF_R(15) TF_R(26) TF_R(6)
    x0 += k1;  x1 += ks2 + 1u;
    TF_R(17) TF_R(29) TF_R(16) TF_R(24)
    x0 += ks2; x1 += k0 + 2u;
    TF_R(13) TF_R(15) TF_R(26) TF_R(6)
    x0 += k0;  x1 += k1 + 3u;
    TF_R(17) TF_R(29) TF_R(16) TF_R(24)
    x0 += k1;  x1 += ks2 + 4u;
    TF_R(13) TF_R(15) TF_R(26) TF_R(6)
    x0 += ks2; x1 += k0 + 5u;
#undef TF_R
    o0 = x0; o1 = x1;
}

__device__ inline uint32_t jax_bits32(uint32_t k0, uint32_t k1, uint32_t idx)
{
    uint32_t a, b;
    tf2x32(k0, k1, 0u, idx, a, b);
    return a ^ b;
}

__device__ inline float jax_u01(uint32_t bits)
{
    return __uint_as_float((bits >> 9) | 0x3f800000u) - 1.0f;
}

// XLA ErfInv32 (Giles 2012)
__device__ inline float erfinv_f(float x)
{
    float w = -log1pf(-x * x);
    float p;
    if (w < 5.0f) {
        w = w - 2.5f;
        p = 2.81022636e-08f;
        p = fmaf(p, w, 3.43273939e-07f);
        p = fmaf(p, w, -3.5233877e-06f);
        p = fmaf(p, w, -4.39150654e-06f);
        p = fmaf(p, w, 0.00021858087f);
        p = fmaf(p, w, -0.00125372503f);
        p = fmaf(p, w, -0.00417768164f);
        p = fmaf(p, w, 0.246640727f);
        p = fmaf(p, w, 1.50140941f);
    } else {
        w = sqrtf(w) - 3.0f;
        p = -0.000200214257f;
        p = fmaf(p, w, 0.000100950558f);
        p = fmaf(p, w, 0.00134934322f);
        p = fmaf(p, w, -0.00367342844f);
        p = fmaf(p, w, 0.00573950773f);
        p = fmaf(p, w, -0.0076224613f);
        p = fmaf(p, w, 0.00943887047f);
        p = fmaf(p, w, 1.00167406f);
        p = fmaf(p, w, 2.83297682f);
    }
    return p * x;
}

// ======================= utility kernels =======================
__global__ __launch_bounds__(256) void fill_u32_k(uint32_t* p, uint32_t v, int n)
{
    int i = blockIdx.x * blockDim.x + threadIdx.x;
    if (i < n) p[i] = v;
}

__global__ __launch_bounds__(256) void f2bf_vec_k(const float* __restrict__ in,
                                                  uint16_t* __restrict__ out, int n)
{
    int i = (blockIdx.x * blockDim.x + threadIdx.x) * 4;
    if (i >= n) return;
    float4 v = *(const float4*)(in + i);
    out[i + 0] = f2bf(v.x); out[i + 1] = f2bf(v.y);
    out[i + 2] = f2bf(v.z); out[i + 3] = f2bf(v.w);
}

// ======================= weight convert: fp32 [B][K][C] -> bf16 Wt [B*C][K] =======================
struct WSeg { const float* src; int B, K, C, off; };
struct WSegs { WSeg s[18]; };

__global__ __launch_bounds__(256) void wconv_k(WSegs segs, uint16_t* __restrict__ Wt)
{
    WSeg sg = segs.s[blockIdx.y];
    int n = sg.B * sg.K * sg.C;
    int i = blockIdx.x * 256 + threadIdx.x;
    if (i >= n) return;
    int kc = sg.K * sg.C;
    int b = i / kc;
    int rr = i - b * kc;
    int k = rr / sg.C;
    int c = rr - k * sg.C;
    Wt[(size_t)sg.off + (size_t)(b * sg.C + c) * sg.K + k] = f2bf(sg.src[i]);
}

// ======================= CSR build (once per launch) =======================
__global__ __launch_bounds__(256) void hist_k(const int* __restrict__ dst, int* __restrict__ deg)
{
    int e = blockIdx.x * blockDim.x + threadIdx.x;
    if (e < NE) atomicAdd(&deg[dst[e]], 1);
}

#define SCAN_CHUNK 1024
#define SCAN_NBLK  ((NN + SCAN_CHUNK - 1) / SCAN_CHUNK)   // 49

__global__ __launch_bounds__(256) void scan1_k(const int* __restrict__ deg,
                                               int* __restrict__ rowptr,
                                               int* __restrict__ bsums)
{
    __shared__ int lds[256];
    int b = blockIdx.x, t = threadIdx.x;
    int base = b * SCAN_CHUNK + t * 4;
    int v0 = (base + 0 < NN) ? deg[base + 0] : 0;
    int v1 = (base + 1 < NN) ? deg[base + 1] : 0;
    int v2 = (base + 2 < NN) ? deg[base + 2] : 0;
    int v3 = (base + 3 < NN) ? deg[base + 3] : 0;
    int s = v0 + v1 + v2 + v3;
    lds[t] = s;
    __syncthreads();
    for (int off = 1; off < 256; off <<= 1) {
        int x = (t >= off) ? lds[t - off] : 0;
        __syncthreads();
        lds[t] += x;
        __syncthreads();
    }
    int excl = lds[t] - s;
    if (base + 0 < NN) rowptr[base + 0] = excl;
    if (base + 1 < NN) rowptr[base + 1] = excl + v0;
    if (base + 2 < NN) rowptr[base + 2] = excl + v0 + v1;
    if (base + 3 < NN) rowptr[base + 3] = excl + v0 + v1 + v2;
    if (t == 255) bsums[b] = lds[255];
}

__global__ void scan2_k(int* bsums)
{
    if (threadIdx.x == 0 && blockIdx.x == 0) {
        int run = 0;
        for (int i = 0; i < SCAN_NBLK; i++) { int t = bsums[i]; bsums[i] = run; run += t; }
    }
}

__global__ __launch_bounds__(256) void scan3_k(int* __restrict__ rowptr,
                                               const int* __restrict__ bsums,
                                               int* __restrict__ cursor)
{
    int i = blockIdx.x * blockDim.x + threadIdx.x;
    if (i < NN) {
        int r = rowptr[i] + bsums[i / SCAN_CHUNK];
        rowptr[i] = r;
        cursor[i] = r;
    }
    if (i == 0) rowptr[NN] = NE;
}

__global__ __launch_bounds__(256) void csr_scatter_k(const int* __restrict__ src,
                                                     const int* __restrict__ dst,
                                                     int* __restrict__ cursor,
                                                     int* __restrict__ esrc)
{
    int e = blockIdx.x * blockDim.x + threadIdx.x;
    if (e >= NE) return;
    int d = dst[e];
    int pos = atomicAdd(&cursor[d], 1);
    esrc[pos] = src[e];
}

// ======================= bf16 MFMA GEMM =======================
template<int K, int CH>
__global__ __launch_bounds__(256) void gemm_mfma_k(const uint16_t* __restrict__ A,
                                                   const uint16_t* __restrict__ Wt,
                                                   uint16_t* __restrict__ C,
                                                   int Ntot, int relu)
{
    constexpr int KP = K + 8;
    constexpr int KC = K / 8;
    constexpr int NT = CH / 16;
    extern __shared__ uint16_t smem[];
    uint16_t* As = smem;             // 64 x KP
    uint16_t* Ws = smem + 64 * KP;   // CH x KP

    const int tid = threadIdx.x;
    const int row0 = blockIdx.x * 64;
    const int w  = tid >> 6;
    const int l  = tid & 63;
    const int lm = l & 15;
    const int lq = l >> 4;

    for (int i = tid; i < 64 * KC; i += 256) {
        int r = i / KC, c = i - r * KC;
        int gr = row0 + r; if (gr >= NN) gr = NN - 1;
        uint4 vv = *(const uint4*)(A + (size_t)gr * K + c * 8);
        *(uint4*)(As + r * KP + c * 8) = vv;
    }

    const uint16_t* a_base = As + (16 * w + lm) * KP + lq * 8;
    const uint16_t* b_base = Ws + lm * KP + lq * 8;

    const int nchunks = Ntot / CH;
    for (int ch = 0; ch < nchunks; ch++) {
        __syncthreads();
        for (int i = tid; i < CH * KC; i += 256) {
            int r = i / KC, c = i - r * KC;
            uint4 vv = *(const uint4*)(Wt + (size_t)(ch * CH + r) * K + c * 8);
            *(uint4*)(Ws + r * KP + c * 8) = vv;
        }
        __syncthreads();

        floatx4 acc[NT];
#pragma unroll
        for (int nt = 0; nt < NT; nt++) acc[nt] = (floatx4){0.f, 0.f, 0.f, 0.f};

#pragma unroll
        for (int ks = 0; ks < K / 32; ks++) {
            short8 av = *(const short8*)(a_base + ks * 32);
#pragma unroll
            for (int nt = 0; nt < NT; nt++) {
                short8 bv = *(const short8*)(b_base + nt * 16 * KP + ks * 32);
                acc[nt] = __builtin_amdgcn_mfma_f32_16x16x32_bf16(av, bv, acc[nt], 0, 0, 0);
            }
        }

        const int rbase = row0 + 16 * w + lq * 4;
        const int cbase = ch * CH + lm;
#pragma unroll
        for (int nt = 0; nt < NT; nt++) {
#pragma unroll
            for (int r = 0; r < 4; r++) {
                int gr = rbase + r;
                if (gr < NN) {
                    float v = acc[nt][r];
                    if (relu) v = fmaxf(v, 0.0f);
                    C[(size_t)gr * Ntot + cbase + nt * 16] = f2bf(v);
                }
            }
        }
    }
}

// ======================= attention: 2 independent waves/block, LDS broadcast =======================
// qkv layout: [N][3*OD] bf16 rows: [q | k | v]. Wave wv -> node blockIdx.x*2+wv.
// NO __syncthreads: each wave owns a private LDS slice; intra-wave sync via
// wave_lds_sync() (lgkmcnt drain). 128-thr blocks -> 16 wg/CU cap gives 32 waves/CU.
// Phase 1: lanes = (16 edge-slots e x 4 heads h1); scores -> s_sc[wv][j][h1] (<=2-way banks).
// Phase 2: lanes = (4 edge-subslots g x 16 dim-lanes dl); alpha/sn broadcast from LDS.
template<int DH>
__global__ __launch_bounds__(128, 8) void attn_dual_k(const uint16_t* __restrict__ qkv,
                                                      const int* __restrict__ rowptr,
                                                      const int* __restrict__ esrc,
                                                      uint16_t* __restrict__ agg,
                                                      float scale)
{
    constexpr int OD  = NH * DH;     // 128 / 64
    constexpr int STR = 3 * OD;
    constexpr int QU  = DH / 8;      // uint4 loads per head slice (4 / 2)
    constexpr int CAP = 64;          // edges per chunk
    constexpr int NP  = CAP / 16;    // phase-1 passes (4)
    constexpr int FV  = OD / 16;     // dims per lane in phase 2 (8 / 4)

    __shared__ float s_sc[2][CAP][4];
    __shared__ int   s_sn[2][CAP];

    const int wv   = threadIdx.x >> 6;
    const int lane = threadIdx.x & 63;
    const int n    = blockIdx.x * 2 + wv;      // NN % 2 == 0
    const int h1   = lane & 3;
    const int e    = lane >> 2;
    const int g    = lane >> 4;
    const int dl   = lane & 15;
    const int h2   = dl >> 2;                  // head owning dims [dl*FV, dl*FV+FV)

    // q fragment (unpacked fp32) for phase-1 head
    float qf[DH];
    {
        const uint4* q4 = (const uint4*)(qkv + (size_t)n * STR + h1 * DH);
#pragma unroll
        for (int i = 0; i < QU; i++) { uint4 u = q4[i]; unpk8(u, &qf[i * 8]); }
    }

    const int j0 = rowptr[n], j1 = rowptr[n + 1];

    float m = -INFINITY, l = 0.0f;
    float acc[FV];
#pragma unroll
    for (int i = 0; i < FV; i++) acc[i] = 0.0f;

    const int voff = 2 * OD + dl * FV;

    for (int c0 = j0; c0 < j1; c0 += CAP) {
        const int cn = min(j1 - c0, CAP);

        if (lane < cn) s_sn[wv][lane] = esrc[c0 + lane];
        wave_lds_sync();

        // ---- phase 1: scores ----
        float p[NP];
        float lm = -INFINITY;
#pragma unroll
        for (int t = 0; t < NP; t++) {
            const int j = e + 16 * t;
            float s = -INFINITY;
            if (j < cn) {
                const int sn = s_sn[wv][j];
                const uint4* kp = (const uint4*)(qkv + (size_t)sn * STR + OD + h1 * DH);
                s = 0.0f;
#pragma unroll
                for (int i = 0; i < QU; i++) {
                    uint4 u = kp[i];
                    float kf[8];
                    unpk8(u, kf);
                    s = fmaf(qf[i * 8 + 0], kf[0], s); s = fmaf(qf[i * 8 + 1], kf[1], s);
                    s = fmaf(qf[i * 8 + 2], kf[2], s); s = fmaf(qf[i * 8 + 3], kf[3], s);
                    s = fmaf(qf[i * 8 + 4], kf[4], s); s = fmaf(qf[i * 8 + 5], kf[5], s);
                    s = fmaf(qf[i * 8 + 6], kf[6], s); s = fmaf(qf[i * 8 + 7], kf[7], s);
                }
                s *= scale;
            }
            p[t] = s;
            lm = fmaxf(lm, s);
        }
#pragma unroll
        for (int msk = 4; msk <= 32; msk <<= 1) lm = fmaxf(lm, __shfl_xor(lm, msk, 64));
        const float mn = fmaxf(m, lm);
        const float corr = expf(m - mn);   // first chunk: exp(-inf)=0 (acc already 0)
        m = mn;

        float ls = 0.0f;
#pragma unroll
        for (int t = 0; t < NP; t++) {
            const int j = e + 16 * t;
            float pe = 0.0f;
            if (j < cn) {
                pe = expf(p[t] - mn);
                s_sc[wv][j][h1] = pe;
            }
            ls += pe;
        }
#pragma unroll
        for (int msk = 4; msk <= 32; msk <<= 1) ls += __shfl_xor(ls, msk, 64);
        l = l * corr + ls;
        wave_lds_sync();

        // ---- phase 2: 4 edges x 16 dim-lanes per pass ----
        const float c2 = __shfl(corr, h2, 64);   // lane h2 has h1 == h2
#pragma unroll
        for (int i = 0; i < FV; i++) acc[i] *= c2;

        for (int jb = 0; jb < cn; jb += 4) {
            const int j = jb + g;
            if (j < cn) {
                const float alpha = s_sc[wv][j][h2];
                const int sn = s_sn[wv][j];
                if constexpr (FV == 8) {
                    uint4 u = *(const uint4*)(qkv + (size_t)sn * STR + voff);
                    float vf[8];
                    unpk8(u, vf);
#pragma unroll
                    for (int i = 0; i < 8; i++) acc[i] = fmaf(alpha, vf[i], acc[i]);
                } else {
                    uint2 u = *(const uint2*)(qkv + (size_t)sn * STR + voff);
                    acc[0] = fmaf(alpha, bf2f(u.x & 0xffffu), acc[0]);
                    acc[1] = fmaf(alpha, bf2f(u.x >> 16),     acc[1]);
                    acc[2] = fmaf(alpha, bf2f(u.y & 0xffffu), acc[2]);
                    acc[3] = fmaf(alpha, bf2f(u.y >> 16),     acc[3]);
                }
            }
        }
        wave_lds_sync();   // phase-2 LDS reads done before next chunk's s_sn writes
    }

    // ---- epilogue: reduce over g, normalize, write ----
    const float lh = __shfl(l, h2, 64);
    const float inv = (lh > 0.0f) ? 1.0f / lh : 0.0f;
#pragma unroll
    for (int i = 0; i < FV; i++) {
        acc[i] += __shfl_xor(acc[i], 16, 64);
        acc[i] += __shfl_xor(acc[i], 32, 64);
    }
    if (g == 0) {
        uint16_t* op = agg + (size_t)n * OD + dl * FV;
        uint32_t wword[FV / 2];
#pragma unroll
        for (int i = 0; i < FV / 2; i++)
            wword[i] = (uint32_t)f2bf(acc[2 * i] * inv) | ((uint32_t)f2bf(acc[2 * i + 1] * inv) << 16);
        if constexpr (FV == 8) {
            *(uint4*)op = make_uint4(wword[0], wword[1], wword[2], wword[3]);
        } else {
            *(uint2*)op = make_uint2(wword[0], wword[1]);
        }
    }
}

// ======================= norms / dropout / reparam =======================
__global__ __launch_bounds__(256) void norm_relu_drop_k(const uint16_t* __restrict__ in,
                                                        uint16_t* __restrict__ out,
                                                        uint32_t k0, uint32_t k1)
{
    int row = blockIdx.x * 4 + (threadIdx.x >> 6);
    int lane = threadIdx.x & 63;
    if (row >= NN) return;
    const uint16_t* r = in + (size_t)row * 128;
    float a = bf2f(r[lane]), b = bf2f(r[lane + 64]);
    float ss = fmaf(a, a, b * b);
#pragma unroll
    for (int m = 32; m > 0; m >>= 1) ss += __shfl_xor(ss, m, 64);
    float d = fmaxf(sqrtf(ss), 1e-12f);
    float ya = fmaxf(a / d, 0.0f);
    float yb = fmaxf(b / d, 0.0f);
    uint32_t ia = (uint32_t)row * 128u + (uint32_t)lane;
    float ua = jax_u01(jax_bits32(k0, k1, ia));
    float ub = jax_u01(jax_bits32(k0, k1, ia + 64u));
    uint16_t* o = out + (size_t)row * 128;
    o[lane]      = f2bf((ua < 0.5f) ? ya * 2.0f : 0.0f);
    o[lane + 64] = f2bf((ub < 0.5f) ? yb * 2.0f : 0.0f);
}

__global__ __launch_bounds__(256) void norm64_k(const uint16_t* __restrict__ in,
                                                float* __restrict__ out)
{
    int row = blockIdx.x * 4 + (threadIdx.x >> 6);
    int lane = threadIdx.x & 63;
    if (row >= NN) return;
    float a = bf2f(in[(size_t)row * 64 + lane]);
    float ss = a * a;
#pragma unroll
    for (int m = 32; m > 0; m >>= 1) ss += __shfl_xor(ss, m, 64);
    float d = fmaxf(sqrtf(ss), 1e-12f);
    out[(size_t)row * 64 + lane] = a / d;
}

__global__ __launch_bounds__(256) void final_z_k(const float* __restrict__ mu,
                                                 const float* __restrict__ lv,
                                                 float* __restrict__ out,
                                                 uint32_t k0, uint32_t k1)
{
    int i = blockIdx.x * blockDim.x + threadIdx.x;
    if (i >= NN * 64) return;
    const float LO = -0.99999994f; // nextafter(-1, 0) in f32
    float u01 = jax_u01(jax_bits32(k0, k1, (uint32_t)i));
    float u = fmaxf(LO, fmaf(u01, 2.0f, LO));
    float eps = 1.41421354f * erfinv_f(u);
    float stdv = expf(lv[i]) + 1e-12f;
    out[i] = fmaf(eps, stdv, mu[i]);
}

// ======================= host side =======================
struct Bufs {
    uint16_t* Wt;
    uint16_t* feat_bf;
    uint16_t* qkv;
    uint16_t* agg;
    uint16_t* h1;
    uint16_t* h2;
    uint16_t* x;
    float* mu;
    float* lv;
    int* rowptr;
    int* cursor;
    int* bsums;
    int* esrc;
};

static void gemm_launch(int K, const uint16_t* A, const uint16_t* Wt, uint16_t* C,
                        int Ntot, int relu, hipStream_t s)
{
    int grid = (NN + 63) / 64;
    switch (K) {
    case 256: {
        size_t lds = (size_t)(64 + 32) * (256 + 8) * 2;
        gemm_mfma_k<256, 32><<<grid, 256, lds, s>>>(A, Wt, C, Ntot, relu);
        break;
    }
    case 128: {
        size_t lds = (size_t)(64 + 64) * (128 + 8) * 2;
        gemm_mfma_k<128, 64><<<grid, 256, lds, s>>>(A, Wt, C, Ntot, relu);
        break;
    }
    default: {
        size_t lds = (size_t)(64 + 64) * (64 + 8) * 2;
        gemm_mfma_k<64, 64><<<grid, 256, lds, s>>>(A, Wt, C, Ntot, relu);
        break;
    }
    }
}

static void run_gt_layer(const uint16_t* h_in, int K, int od,
                         const uint16_t* wqkv_t, const uint16_t* wo_t, bool relu,
                         uint16_t* h_out, const Bufs& B, hipStream_t stream)
{
    const int dh = od / NH;
    const float scale = 1.0f / sqrtf((float)dh);

    gemm_launch(K, h_in, wqkv_t, B.qkv, 3 * od, 0, stream);

    if (dh == 32)
        attn_dual_k<32><<<NN / 2, 128, 0, stream>>>(B.qkv, B.rowptr, B.esrc, B.agg, scale);
    else
        attn_dual_k<16><<<NN / 2, 128, 0, stream>>>(B.qkv, B.rowptr, B.esrc, B.agg, scale);

    gemm_launch(od, B.agg, wo_t, h_out, od, relu ? 1 : 0, stream);
}

extern "C" void kernel_launch(void* const* d_in, const int* in_sizes, int n_in,
                              void* d_out, int out_size, void* d_ws, size_t ws_size,
                              hipStream_t stream)
{
    const float* feat    = (const float*)d_in[0];
    const int*   src     = (const int*)d_in[1];
    const int*   dst     = (const int*)d_in[2];
    const float* wqkv1_0 = (const float*)d_in[3];
    const float* wqkv1_r = (const float*)d_in[4];
    const float* wo1     = (const float*)d_in[5];
    const float* wqkv2_0 = (const float*)d_in[6];
    const float* wqkv2_r = (const float*)d_in[7];
    const float* wo2     = (const float*)d_in[8];
    const float* wqkv3_0 = (const float*)d_in[9];
    const float* wqkv3_r = (const float*)d_in[10];
    const float* wo3     = (const float*)d_in[11];
    float* out = (float*)d_out;

    char* wp = (char*)d_ws;
    auto alloc = [&](size_t bytes) { char* p = wp; wp += (bytes + 255) & ~(size_t)255; return p; };

    WSegs segs;
    int offs[18];
    int acc_off = 0;
    auto seg = [&](int i, const float* p, int Bc, int Kc, int Cc) {
        segs.s[i].src = p; segs.s[i].B = Bc; segs.s[i].K = Kc; segs.s[i].C = Cc;
        segs.s[i].off = acc_off; offs[i] = acc_off; acc_off += Bc * Kc * Cc;
    };
    seg(0,  wqkv1_0,                 3, 256, 128);
    seg(1,  wqkv1_r,                 3, 128, 128);
    seg(2,  wqkv1_r + 3 * 128 * 128, 3, 128, 128);
    seg(3,  wo1,                     1, 128, 128);
    seg(4,  wo1 + 128 * 128,         1, 128, 128);
    seg(5,  wo1 + 2 * 128 * 128,     1, 128, 128);
    seg(6,  wqkv2_0,                 3, 128, 64);
    seg(7,  wqkv2_r,                 3, 64, 64);
    seg(8,  wqkv2_r + 3 * 64 * 64,   3, 64, 64);
    seg(9,  wo2,                     1, 64, 64);
    seg(10, wo2 + 64 * 64,           1, 64, 64);
    seg(11, wo2 + 2 * 64 * 64,       1, 64, 64);
    seg(12, wqkv3_0,                 3, 128, 64);
    seg(13, wqkv3_r,                 3, 64, 64);
    seg(14, wqkv3_r + 3 * 64 * 64,   3, 64, 64);
    seg(15, wo3,                     1, 64, 64);
    seg(16, wo3 + 64 * 64,           1, 64, 64);
    seg(17, wo3 + 2 * 64 * 64,       1, 64, 64);

    Bufs B;
    B.Wt      = (uint16_t*)alloc((size_t)acc_off * 2);
    B.feat_bf = (uint16_t*)alloc((size_t)NN * 256 * 2);
    B.qkv     = (uint16_t*)alloc((size_t)NN * 384 * 2);
    B.agg     = (uint16_t*)alloc((size_t)NN * 128 * 2);
    B.h1      = (uint16_t*)alloc((size_t)NN * 128 * 2);
    B.h2      = (uint16_t*)alloc((size_t)NN * 128 * 2);
    B.x       = (uint16_t*)alloc((size_t)NN * 128 * 2);
    B.mu      = (float*)alloc((size_t)NN * 64 * 4);
    B.lv      = (float*)alloc((size_t)NN * 64 * 4);
    B.rowptr  = (int*)alloc((size_t)(NN + 1) * 4);
    B.cursor  = (int*)alloc((size_t)NN * 4);
    B.bsums   = (int*)alloc((size_t)SCAN_NBLK * 4);
    B.esrc    = (int*)alloc((size_t)NE * 4);

    wconv_k<<<dim3(384, 18), 256, 0, stream>>>(segs, B.Wt);
    f2bf_vec_k<<<(NN * 256 / 4 + 255) / 256, 256, 0, stream>>>(feat, B.feat_bf, NN * 256);

    fill_u32_k<<<(NN + 255) / 256, 256, 0, stream>>>((uint32_t*)B.cursor, 0u, NN);
    hist_k<<<(NE + 255) / 256, 256, 0, stream>>>(dst, B.cursor);
    scan1_k<<<SCAN_NBLK, 256, 0, stream>>>(B.cursor, B.rowptr, B.bsums);
    scan2_k<<<1, 64, 0, stream>>>(B.bsums);
    scan3_k<<<(NN + 255) / 256, 256, 0, stream>>>(B.rowptr, B.bsums, B.cursor);
    csr_scatter_k<<<(NE + 255) / 256, 256, 0, stream>>>(src, dst, B.cursor, B.esrc);

    uint32_t kd0, kd1, ke0, ke1;
    tf2x32(0u, 42u, 0u, 0u, kd0, kd1);
    tf2x32(0u, 42u, 0u, 1u, ke0, ke1);

    run_gt_layer(B.feat_bf, 256, 128, B.Wt + offs[0], B.Wt + offs[3], true,  B.h1, B, stream);
    run_gt_layer(B.h1,      128, 128, B.Wt + offs[1], B.Wt + offs[4], true,  B.h2, B, stream);
    run_gt_layer(B.h2,      128, 128, B.Wt + offs[2], B.Wt + offs[5], false, B.h1, B, stream);

    norm_relu_drop_k<<<NN / 4, 256, 0, stream>>>(B.h1, B.x, kd0, kd1);

    run_gt_layer(B.x,  128, 64, B.Wt + offs[6], B.Wt + offs[9],  true,  B.h1, B, stream);
    run_gt_layer(B.h1, 64,  64, B.Wt + offs[7], B.Wt + offs[10], true,  B.h2, B, stream);
    run_gt_layer(B.h2, 64,  64, B.Wt + offs[8], B.Wt + offs[11], false, B.h1, B, stream);
    norm64_k<<<NN / 4, 256, 0, stream>>>(B.h1, B.mu);

    run_gt_layer(B.x,  128, 64, B.Wt + offs[12], B.Wt + offs[15], true,  B.h1, B, stream);
    run_gt_layer(B.h1, 64,  64, B.Wt + offs[13], B.Wt + offs[16], true,  B.h2, B, stream);
    run_gt_layer(B.h2, 64,  64, B.Wt + offs[14], B.Wt + offs[17], false, B.h1, B, stream);
    norm64_k<<<NN / 4, 256, 0, stream>>>(B.h1, B.lv);

    final_z_k<<<(NN * 64 + 255) / 256, 256, 0, stream>>>(B.mu, B.lv, out, ke0, ke1);
}

// Round 9
// 898.477 us; speedup vs baseline: 1.2759x; 1.2759x over previous
//
#include <hip/hip_runtime.h>
#include <stdint.h>
#include <math.h>

#define NN 50000          // nodes
#define NE 800000         // edges
#define NH 4              // heads

typedef __attribute__((ext_vector_type(8))) short short8;
typedef __attribute__((ext_vector_type(4))) float floatx4;

// ======================= bf16 helpers =======================
__device__ inline float bf2f(uint32_t u16)
{
    return __uint_as_float(u16 << 16);
}
__device__ inline uint16_t f2bf(float f)
{
    uint32_t u = __float_as_uint(f);
    uint32_t r = (u + 0x7fffu + ((u >> 16) & 1u)) >> 16;   // RNE
    return (uint16_t)r;
}
__device__ inline void unpk8(uint4 u, float* f)
{
    f[0] = bf2f(u.x & 0xffffu); f[1] = bf2f(u.x >> 16);
    f[2] = bf2f(u.y & 0xffffu); f[3] = bf2f(u.y >> 16);
    f[4] = bf2f(u.z & 0xffffu); f[5] = bf2f(u.z >> 16);
    f[6] = bf2f(u.w & 0xffffu); f[7] = bf2f(u.w >> 16);
}

// intra-wave LDS producer->consumer sync (single wave; no __syncthreads needed)
__device__ inline void wave_lds_sync()
{
    __builtin_amdgcn_wave_barrier();
    asm volatile("s_waitcnt lgkmcnt(0)" ::: "memory");
    __builtin_amdgcn_wave_barrier();
}

// ======================= JAX threefry2x32 (partitionable mode) =======================
__host__ __device__ inline void tf2x32(uint32_t k0, uint32_t k1,
                                       uint32_t x0, uint32_t x1,
                                       uint32_t& o0, uint32_t& o1)
{
    uint32_t ks2 = k0 ^ k1 ^ 0x1BD11BDAu;
    x0 += k0; x1 += k1;
#define TF_R(r) { x0 += x1; x1 = (x1 << (r)) | (x1 >> (32 - (r))); x1 ^= x0; }
    TF_R(13) TF_R(15) TF_R(26) TF_R(6)
    x0 += k1;  x1 += ks2 + 1u;
    TF_R(17) TF_R(29) TF_R(16) TF_R(24)
    x0 += ks2; x1 += k0 + 2u;
    TF_R(13) TF_R(15) TF_R(26) TF_R(6)
    x0 += k0;  x1 += k1 + 3u;
    TF_R(17) TF_R(29) TF_R(16) TF_R(24)
    x0 += k1;  x1 += ks2 + 4u;
    TF_R(13) TF_R(15) TF_R(26) TF_R(6)
    x0 += ks2; x1 += k0 + 5u;
#undef TF_R
    o0 = x0; o1 = x1;
}

__device__ inline uint32_t jax_bits32(uint32_t k0, uint32_t k1, uint32_t idx)
{
    uint32_t a, b;
    tf2x32(k0, k1, 0u, idx, a, b);
    return a ^ b;
}

__device__ inline float jax_u01(uint32_t bits)
{
    return __uint_as_float((bits >> 9) | 0x3f800000u) - 1.0f;
}

// XLA ErfInv32 (Giles 2012)
__device__ inline float erfinv_f(float x)
{
    float w = -log1pf(-x * x);
    float p;
    if (w < 5.0f) {
        w = w - 2.5f;
        p = 2.81022636e-08f;
        p = fmaf(p, w, 3.43273939e-07f);
        p = fmaf(p, w, -3.5233877e-06f);
        p = fmaf(p, w, -4.39150654e-06f);
        p = fmaf(p, w, 0.00021858087f);
        p = fmaf(p, w, -0.00125372503f);
        p = fmaf(p, w, -0.00417768164f);
        p = fmaf(p, w, 0.246640727f);
        p = fmaf(p, w, 1.50140941f);
    } else {
        w = sqrtf(w) - 3.0f;
        p = -0.000200214257f;
        p = fmaf(p, w, 0.000100950558f);
        p = fmaf(p, w, 0.00134934322f);
        p = fmaf(p, w, -0.00367342844f);
        p = fmaf(p, w, 0.00573950773f);
        p = fmaf(p, w, -0.0076224613f);
        p = fmaf(p, w, 0.00943887047f);
        p = fmaf(p, w, 1.00167406f);
        p = fmaf(p, w, 2.83297682f);
    }
    return p * x;
}

// ======================= utility kernels =======================
__global__ __launch_bounds__(256) void fill_u32_k(uint32_t* p, uint32_t v, int n)
{
    int i = blockIdx.x * blockDim.x + threadIdx.x;
    if (i < n) p[i] = v;
}

__global__ __launch_bounds__(256) void f2bf_vec_k(const float* __restrict__ in,
                                                  uint16_t* __restrict__ out, int n)
{
    int i = (blockIdx.x * blockDim.x + threadIdx.x) * 4;
    if (i >= n) return;
    float4 v = *(const float4*)(in + i);
    out[i + 0] = f2bf(v.x); out[i + 1] = f2bf(v.y);
    out[i + 2] = f2bf(v.z); out[i + 3] = f2bf(v.w);
}

// ======================= weight convert: fp32 [B][K][C] -> bf16 Wt [B*C][K] =======================
struct WSeg { const float* src; int B, K, C, off; };
struct WSegs { WSeg s[18]; };

__global__ __launch_bounds__(256) void wconv_k(WSegs segs, uint16_t* __restrict__ Wt)
{
    WSeg sg = segs.s[blockIdx.y];
    int n = sg.B * sg.K * sg.C;
    int i = blockIdx.x * 256 + threadIdx.x;
    if (i >= n) return;
    int kc = sg.K * sg.C;
    int b = i / kc;
    int rr = i - b * kc;
    int k = rr / sg.C;
    int c = rr - k * sg.C;
    Wt[(size_t)sg.off + (size_t)(b * sg.C + c) * sg.K + k] = f2bf(sg.src[i]);
}

// ======================= CSR build (once per launch) =======================
__global__ __launch_bounds__(256) void hist_k(const int* __restrict__ dst, int* __restrict__ deg)
{
    int e = blockIdx.x * blockDim.x + threadIdx.x;
    if (e < NE) atomicAdd(&deg[dst[e]], 1);
}

#define SCAN_CHUNK 1024
#define SCAN_NBLK  ((NN + SCAN_CHUNK - 1) / SCAN_CHUNK)   // 49

__global__ __launch_bounds__(256) void scan1_k(const int* __restrict__ deg,
                                               int* __restrict__ rowptr,
                                               int* __restrict__ bsums)
{
    __shared__ int lds[256];
    int b = blockIdx.x, t = threadIdx.x;
    int base = b * SCAN_CHUNK + t * 4;
    int v0 = (base + 0 < NN) ? deg[base + 0] : 0;
    int v1 = (base + 1 < NN) ? deg[base + 1] : 0;
    int v2 = (base + 2 < NN) ? deg[base + 2] : 0;
    int v3 = (base + 3 < NN) ? deg[base + 3] : 0;
    int s = v0 + v1 + v2 + v3;
    lds[t] = s;
    __syncthreads();
    for (int off = 1; off < 256; off <<= 1) {
        int x = (t >= off) ? lds[t - off] : 0;
        __syncthreads();
        lds[t] += x;
        __syncthreads();
    }
    int excl = lds[t] - s;
    if (base + 0 < NN) rowptr[base + 0] = excl;
    if (base + 1 < NN) rowptr[base + 1] = excl + v0;
    if (base + 2 < NN) rowptr[base + 2] = excl + v0 + v1;
    if (base + 3 < NN) rowptr[base + 3] = excl + v0 + v1 + v2;
    if (t == 255) bsums[b] = lds[255];
}

__global__ void scan2_k(int* bsums)
{
    if (threadIdx.x == 0 && blockIdx.x == 0) {
        int run = 0;
        for (int i = 0; i < SCAN_NBLK; i++) { int t = bsums[i]; bsums[i] = run; run += t; }
    }
}

__global__ __launch_bounds__(256) void scan3_k(int* __restrict__ rowptr,
                                               const int* __restrict__ bsums,
                                               int* __restrict__ cursor)
{
    int i = blockIdx.x * blockDim.x + threadIdx.x;
    if (i < NN) {
        int r = rowptr[i] + bsums[i / SCAN_CHUNK];
        rowptr[i] = r;
        cursor[i] = r;
    }
    if (i == 0) rowptr[NN] = NE;
}

__global__ __launch_bounds__(256) void csr_scatter_k(const int* __restrict__ src,
                                                     const int* __restrict__ dst,
                                                     int* __restrict__ cursor,
                                                     int* __restrict__ esrc)
{
    int e = blockIdx.x * blockDim.x + threadIdx.x;
    if (e >= NE) return;
    int d = dst[e];
    int pos = atomicAdd(&cursor[d], 1);
    esrc[pos] = src[e];
}

// ======================= bf16 MFMA GEMM =======================
template<int K, int CH>
__global__ __launch_bounds__(256) void gemm_mfma_k(const uint16_t* __restrict__ A,
                                                   const uint16_t* __restrict__ Wt,
                                                   uint16_t* __restrict__ C,
                                                   int Ntot, int relu)
{
    constexpr int KP = K + 8;
    constexpr int KC = K / 8;
    constexpr int NT = CH / 16;
    extern __shared__ uint16_t smem[];
    uint16_t* As = smem;             // 64 x KP
    uint16_t* Ws = smem + 64 * KP;   // CH x KP

    const int tid = threadIdx.x;
    const int row0 = blockIdx.x * 64;
    const int w  = tid >> 6;
    const int l  = tid & 63;
    const int lm = l & 15;
    const int lq = l >> 4;

    for (int i = tid; i < 64 * KC; i += 256) {
        int r = i / KC, c = i - r * KC;
        int gr = row0 + r; if (gr >= NN) gr = NN - 1;
        uint4 vv = *(const uint4*)(A + (size_t)gr * K + c * 8);
        *(uint4*)(As + r * KP + c * 8) = vv;
    }

    const uint16_t* a_base = As + (16 * w + lm) * KP + lq * 8;
    const uint16_t* b_base = Ws + lm * KP + lq * 8;

    const int nchunks = Ntot / CH;
    for (int ch = 0; ch < nchunks; ch++) {
        __syncthreads();
        for (int i = tid; i < CH * KC; i += 256) {
            int r = i / KC, c = i - r * KC;
            uint4 vv = *(const uint4*)(Wt + (size_t)(ch * CH + r) * K + c * 8);
            *(uint4*)(Ws + r * KP + c * 8) = vv;
        }
        __syncthreads();

        floatx4 acc[NT];
#pragma unroll
        for (int nt = 0; nt < NT; nt++) acc[nt] = (floatx4){0.f, 0.f, 0.f, 0.f};

#pragma unroll
        for (int ks = 0; ks < K / 32; ks++) {
            short8 av = *(const short8*)(a_base + ks * 32);
#pragma unroll
            for (int nt = 0; nt < NT; nt++) {
                short8 bv = *(const short8*)(b_base + nt * 16 * KP + ks * 32);
                acc[nt] = __builtin_amdgcn_mfma_f32_16x16x32_bf16(av, bv, acc[nt], 0, 0, 0);
            }
        }

        const int rbase = row0 + 16 * w + lq * 4;
        const int cbase = ch * CH + lm;
#pragma unroll
        for (int nt = 0; nt < NT; nt++) {
#pragma unroll
            for (int r = 0; r < 4; r++) {
                int gr = rbase + r;
                if (gr < NN) {
                    float v = acc[nt][r];
                    if (relu) v = fmaxf(v, 0.0f);
                    C[(size_t)gr * Ntot + cbase + nt * 16] = f2bf(v);
                }
            }
        }
    }
}

// ======================= attention: 2 independent waves/block, LDS broadcast =======================
// qkv layout: [N][3*OD] bf16 rows: [q | k | v]. Wave wv -> node blockIdx.x*2+wv.
// NO __syncthreads: each wave owns a private LDS slice; intra-wave sync via
// wave_lds_sync() (lgkmcnt drain). 128-thr blocks -> 16 wg/CU x 2 waves = 32 waves/CU.
// NOTE: no min-waves in __launch_bounds__ — R7's (128,8) forced VGPR cap -> 300 MB
// scratch spill traffic (WRITE_SIZE counter). Natural allocation (~56-64 VGPR)
// still allows 8 waves/SIMD.
template<int DH>
__global__ __launch_bounds__(128) void attn_dual_k(const uint16_t* __restrict__ qkv,
                                                   const int* __restrict__ rowptr,
                                                   const int* __restrict__ esrc,
                                                   uint16_t* __restrict__ agg,
                                                   float scale)
{
    constexpr int OD  = NH * DH;     // 128 / 64
    constexpr int STR = 3 * OD;
    constexpr int QU  = DH / 8;      // uint4 loads per head slice (4 / 2)
    constexpr int CAP = 64;          // edges per chunk
    constexpr int NP  = CAP / 16;    // phase-1 passes (4)
    constexpr int FV  = OD / 16;     // dims per lane in phase 2 (8 / 4)

    __shared__ float s_sc[2][CAP][4];
    __shared__ int   s_sn[2][CAP];

    const int wv   = threadIdx.x >> 6;
    const int lane = threadIdx.x & 63;
    const int n    = blockIdx.x * 2 + wv;      // NN % 2 == 0
    const int h1   = lane & 3;
    const int e    = lane >> 2;
    const int g    = lane >> 4;
    const int dl   = lane & 15;
    const int h2   = dl >> 2;                  // head owning dims [dl*FV, dl*FV+FV)

    // q fragment (unpacked fp32) for phase-1 head
    float qf[DH];
    {
        const uint4* q4 = (const uint4*)(qkv + (size_t)n * STR + h1 * DH);
#pragma unroll
        for (int i = 0; i < QU; i++) { uint4 u = q4[i]; unpk8(u, &qf[i * 8]); }
    }

    const int j0 = rowptr[n], j1 = rowptr[n + 1];

    float m = -INFINITY, l = 0.0f;
    float acc[FV];
#pragma unroll
    for (int i = 0; i < FV; i++) acc[i] = 0.0f;

    const int voff = 2 * OD + dl * FV;

    for (int c0 = j0; c0 < j1; c0 += CAP) {
        const int cn = min(j1 - c0, CAP);

        if (lane < cn) s_sn[wv][lane] = esrc[c0 + lane];
        wave_lds_sync();

        // ---- phase 1: scores ----
        float p[NP];
        float lm = -INFINITY;
#pragma unroll
        for (int t = 0; t < NP; t++) {
            const int j = e + 16 * t;
            float s = -INFINITY;
            if (j < cn) {
                const int sn = s_sn[wv][j];
                const uint4* kp = (const uint4*)(qkv + (size_t)sn * STR + OD + h1 * DH);
                s = 0.0f;
#pragma unroll
                for (int i = 0; i < QU; i++) {
                    uint4 u = kp[i];
                    float kf[8];
                    unpk8(u, kf);
                    s = fmaf(qf[i * 8 + 0], kf[0], s); s = fmaf(qf[i * 8 + 1], kf[1], s);
                    s = fmaf(qf[i * 8 + 2], kf[2], s); s = fmaf(qf[i * 8 + 3], kf[3], s);
                    s = fmaf(qf[i * 8 + 4], kf[4], s); s = fmaf(qf[i * 8 + 5], kf[5], s);
                    s = fmaf(qf[i * 8 + 6], kf[6], s); s = fmaf(qf[i * 8 + 7], kf[7], s);
                }
                s *= scale;
            }
            p[t] = s;
            lm = fmaxf(lm, s);
        }
#pragma unroll
        for (int msk = 4; msk <= 32; msk <<= 1) lm = fmaxf(lm, __shfl_xor(lm, msk, 64));
        const float mn = fmaxf(m, lm);
        const float corr = expf(m - mn);   // first chunk: exp(-inf)=0 (acc already 0)
        m = mn;

        float ls = 0.0f;
#pragma unroll
        for (int t = 0; t < NP; t++) {
            const int j = e + 16 * t;
            float pe = 0.0f;
            if (j < cn) {
                pe = expf(p[t] - mn);
                s_sc[wv][j][h1] = pe;
            }
            ls += pe;
        }
#pragma unroll
        for (int msk = 4; msk <= 32; msk <<= 1) ls += __shfl_xor(ls, msk, 64);
        l = l * corr + ls;
        wave_lds_sync();

        // ---- phase 2: 4 edges x 16 dim-lanes per pass ----
        const float c2 = __shfl(corr, h2, 64);   // lane h2 has h1 == h2
#pragma unroll
        for (int i = 0; i < FV; i++) acc[i] *= c2;

        for (int jb = 0; jb < cn; jb += 4) {
            const int j = jb + g;
            if (j < cn) {
                const float alpha = s_sc[wv][j][h2];
                const int sn = s_sn[wv][j];
                if constexpr (FV == 8) {
                    uint4 u = *(const uint4*)(qkv + (size_t)sn * STR + voff);
                    float vf[8];
                    unpk8(u, vf);
#pragma unroll
                    for (int i = 0; i < 8; i++) acc[i] = fmaf(alpha, vf[i], acc[i]);
                } else {
                    uint2 u = *(const uint2*)(qkv + (size_t)sn * STR + voff);
                    acc[0] = fmaf(alpha, bf2f(u.x & 0xffffu), acc[0]);
                    acc[1] = fmaf(alpha, bf2f(u.x >> 16),     acc[1]);
                    acc[2] = fmaf(alpha, bf2f(u.y & 0xffffu), acc[2]);
                    acc[3] = fmaf(alpha, bf2f(u.y >> 16),     acc[3]);
                }
            }
        }
        wave_lds_sync();   // phase-2 LDS reads done before next chunk's s_sn writes
    }

    // ---- epilogue: reduce over g, normalize, write ----
    const float lh = __shfl(l, h2, 64);
    const float inv = (lh > 0.0f) ? 1.0f / lh : 0.0f;
#pragma unroll
    for (int i = 0; i < FV; i++) {
        acc[i] += __shfl_xor(acc[i], 16, 64);
        acc[i] += __shfl_xor(acc[i], 32, 64);
    }
    if (g == 0) {
        uint16_t* op = agg + (size_t)n * OD + dl * FV;
        uint32_t wword[FV / 2];
#pragma unroll
        for (int i = 0; i < FV / 2; i++)
            wword[i] = (uint32_t)f2bf(acc[2 * i] * inv) | ((uint32_t)f2bf(acc[2 * i + 1] * inv) << 16);
        if constexpr (FV == 8) {
            *(uint4*)op = make_uint4(wword[0], wword[1], wword[2], wword[3]);
        } else {
            *(uint2*)op = make_uint2(wword[0], wword[1]);
        }
    }
}

// ======================= norms / dropout / reparam =======================
__global__ __launch_bounds__(256) void norm_relu_drop_k(const uint16_t* __restrict__ in,
                                                        uint16_t* __restrict__ out,
                                                        uint32_t k0, uint32_t k1)
{
    int row = blockIdx.x * 4 + (threadIdx.x >> 6);
    int lane = threadIdx.x & 63;
    if (row >= NN) return;
    const uint16_t* r = in + (size_t)row * 128;
    float a = bf2f(r[lane]), b = bf2f(r[lane + 64]);
    float ss = fmaf(a, a, b * b);
#pragma unroll
    for (int m = 32; m > 0; m >>= 1) ss += __shfl_xor(ss, m, 64);
    float d = fmaxf(sqrtf(ss), 1e-12f);
    float ya = fmaxf(a / d, 0.0f);
    float yb = fmaxf(b / d, 0.0f);
    uint32_t ia = (uint32_t)row * 128u + (uint32_t)lane;
    float ua = jax_u01(jax_bits32(k0, k1, ia));
    float ub = jax_u01(jax_bits32(k0, k1, ia + 64u));
    uint16_t* o = out + (size_t)row * 128;
    o[lane]      = f2bf((ua < 0.5f) ? ya * 2.0f : 0.0f);
    o[lane + 64] = f2bf((ub < 0.5f) ? yb * 2.0f : 0.0f);
}

__global__ __launch_bounds__(256) void norm64_k(const uint16_t* __restrict__ in,
                                                float* __restrict__ out)
{
    int row = blockIdx.x * 4 + (threadIdx.x >> 6);
    int lane = threadIdx.x & 63;
    if (row >= NN) return;
    float a = bf2f(in[(size_t)row * 64 + lane]);
    float ss = a * a;
#pragma unroll
    for (int m = 32; m > 0; m >>= 1) ss += __shfl_xor(ss, m, 64);
    float d = fmaxf(sqrtf(ss), 1e-12f);
    out[(size_t)row * 64 + lane] = a / d;
}

__global__ __launch_bounds__(256) void final_z_k(const float* __restrict__ mu,
                                                 const float* __restrict__ lv,
                                                 float* __restrict__ out,
                                                 uint32_t k0, uint32_t k1)
{
    int i = blockIdx.x * blockDim.x + threadIdx.x;
    if (i >= NN * 64) return;
    const float LO = -0.99999994f; // nextafter(-1, 0) in f32
    float u01 = jax_u01(jax_bits32(k0, k1, (uint32_t)i));
    float u = fmaxf(LO, fmaf(u01, 2.0f, LO));
    float eps = 1.41421354f * erfinv_f(u);
    float stdv = expf(lv[i]) + 1e-12f;
    out[i] = fmaf(eps, stdv, mu[i]);
}

// ======================= host side =======================
struct Bufs {
    uint16_t* Wt;
    uint16_t* feat_bf;
    uint16_t* qkv;
    uint16_t* agg;
    uint16_t* h1;
    uint16_t* h2;
    uint16_t* x;
    float* mu;
    float* lv;
    int* rowptr;
    int* cursor;
    int* bsums;
    int* esrc;
};

static void gemm_launch(int K, const uint16_t* A, const uint16_t* Wt, uint16_t* C,
                        int Ntot, int relu, hipStream_t s)
{
    int grid = (NN + 63) / 64;
    switch (K) {
    case 256: {
        size_t lds = (size_t)(64 + 32) * (256 + 8) * 2;
        gemm_mfma_k<256, 32><<<grid, 256, lds, s>>>(A, Wt, C, Ntot, relu);
        break;
    }
    case 128: {
        size_t lds = (size_t)(64 + 64) * (128 + 8) * 2;
        gemm_mfma_k<128, 64><<<grid, 256, lds, s>>>(A, Wt, C, Ntot, relu);
        break;
    }
    default: {
        size_t lds = (size_t)(64 + 64) * (64 + 8) * 2;
        gemm_mfma_k<64, 64><<<grid, 256, lds, s>>>(A, Wt, C, Ntot, relu);
        break;
    }
    }
}

static void run_gt_layer(const uint16_t* h_in, int K, int od,
                         const uint16_t* wqkv_t, const uint16_t* wo_t, bool relu,
                         uint16_t* h_out, const Bufs& B, hipStream_t stream)
{
    const int dh = od / NH;
    const float scale = 1.0f / sqrtf((float)dh);

    gemm_launch(K, h_in, wqkv_t, B.qkv, 3 * od, 0, stream);

    if (dh == 32)
        attn_dual_k<32><<<NN / 2, 128, 0, stream>>>(B.qkv, B.rowptr, B.esrc, B.agg, scale);
    else
        attn_dual_k<16><<<NN / 2, 128, 0, stream>>>(B.qkv, B.rowptr, B.esrc, B.agg, scale);

    gemm_launch(od, B.agg, wo_t, h_out, od, relu ? 1 : 0, stream);
}

extern "C" void kernel_launch(void* const* d_in, const int* in_sizes, int n_in,
                              void* d_out, int out_size, void* d_ws, size_t ws_size,
                              hipStream_t stream)
{
    const float* feat    = (const float*)d_in[0];
    const int*   src     = (const int*)d_in[1];
    const int*   dst     = (const int*)d_in[2];
    const float* wqkv1_0 = (const float*)d_in[3];
    const float* wqkv1_r = (const float*)d_in[4];
    const float* wo1     = (const float*)d_in[5];
    const float* wqkv2_0 = (const float*)d_in[6];
    const float* wqkv2_r = (const float*)d_in[7];
    const float* wo2     = (const float*)d_in[8];
    const float* wqkv3_0 = (const float*)d_in[9];
    const float* wqkv3_r = (const float*)d_in[10];
    const float* wo3     = (const float*)d_in[11];
    float* out = (float*)d_out;

    char* wp = (char*)d_ws;
    auto alloc = [&](size_t bytes) { char* p = wp; wp += (bytes + 255) & ~(size_t)255; return p; };

    WSegs segs;
    int offs[18];
    int acc_off = 0;
    auto seg = [&](int i, const float* p, int Bc, int Kc, int Cc) {
        segs.s[i].src = p; segs.s[i].B = Bc; segs.s[i].K = Kc; segs.s[i].C = Cc;
        segs.s[i].off = acc_off; offs[i] = acc_off; acc_off += Bc * Kc * Cc;
    };
    seg(0,  wqkv1_0,                 3, 256, 128);
    seg(1,  wqkv1_r,                 3, 128, 128);
    seg(2,  wqkv1_r + 3 * 128 * 128, 3, 128, 128);
    seg(3,  wo1,                     1, 128, 128);
    seg(4,  wo1 + 128 * 128,         1, 128, 128);
    seg(5,  wo1 + 2 * 128 * 128,     1, 128, 128);
    seg(6,  wqkv2_0,                 3, 128, 64);
    seg(7,  wqkv2_r,                 3, 64, 64);
    seg(8,  wqkv2_r + 3 * 64 * 64,   3, 64, 64);
    seg(9,  wo2,                     1, 64, 64);
    seg(10, wo2 + 64 * 64,           1, 64, 64);
    seg(11, wo2 + 2 * 64 * 64,       1, 64, 64);
    seg(12, wqkv3_0,                 3, 128, 64);
    seg(13, wqkv3_r,                 3, 64, 64);
    seg(14, wqkv3_r + 3 * 64 * 64,   3, 64, 64);
    seg(15, wo3,                     1, 64, 64);
    seg(16, wo3 + 64 * 64,           1, 64, 64);
    seg(17, wo3 + 2 * 64 * 64,       1, 64, 64);

    Bufs B;
    B.Wt      = (uint16_t*)alloc((size_t)acc_off * 2);
    B.feat_bf = (uint16_t*)alloc((size_t)NN * 256 * 2);
    B.qkv     = (uint16_t*)alloc((size_t)NN * 384 * 2);
    B.agg     = (uint16_t*)alloc((size_t)NN * 128 * 2);
    B.h1      = (uint16_t*)alloc((size_t)NN * 128 * 2);
    B.h2      = (uint16_t*)alloc((size_t)NN * 128 * 2);
    B.x       = (uint16_t*)alloc((size_t)NN * 128 * 2);
    B.mu      = (float*)alloc((size_t)NN * 64 * 4);
    B.lv      = (float*)alloc((size_t)NN * 64 * 4);
    B.rowptr  = (int*)alloc((size_t)(NN + 1) * 4);
    B.cursor  = (int*)alloc((size_t)NN * 4);
    B.bsums   = (int*)alloc((size_t)SCAN_NBLK * 4);
    B.esrc    = (int*)alloc((size_t)NE * 4);

    wconv_k<<<dim3(384, 18), 256, 0, stream>>>(segs, B.Wt);
    f2bf_vec_k<<<(NN * 256 / 4 + 255) / 256, 256, 0, stream>>>(feat, B.feat_bf, NN * 256);

    fill_u32_k<<<(NN + 255) / 256, 256, 0, stream>>>((uint32_t*)B.cursor, 0u, NN);
    hist_k<<<(NE + 255) / 256, 256, 0, stream>>>(dst, B.cursor);
    scan1_k<<<SCAN_NBLK, 256, 0, stream>>>(B.cursor, B.rowptr, B.bsums);
    scan2_k<<<1, 64, 0, stream>>>(B.bsums);
    scan3_k<<<(NN + 255) / 256, 256, 0, stream>>>(B.rowptr, B.bsums, B.cursor);
    csr_scatter_k<<<(NE + 255) / 256, 256, 0, stream>>>(src, dst, B.cursor, B.esrc);

    uint32_t kd0, kd1, ke0, ke1;
    tf2x32(0u, 42u, 0u, 0u, kd0, kd1);
    tf2x32(0u, 42u, 0u, 1u, ke0, ke1);

    run_gt_layer(B.feat_bf, 256, 128, B.Wt + offs[0], B.Wt + offs[3], true,  B.h1, B, stream);
    run_gt_layer(B.h1,      128, 128, B.Wt + offs[1], B.Wt + offs[4], true,  B.h2, B, stream);
    run_gt_layer(B.h2,      128, 128, B.Wt + offs[2], B.Wt + offs[5], false, B.h1, B, stream);

    norm_relu_drop_k<<<NN / 4, 256, 0, stream>>>(B.h1, B.x, kd0, kd1);

    run_gt_layer(B.x,  128, 64, B.Wt + offs[6], B.Wt + offs[9],  true,  B.h1, B, stream);
    run_gt_layer(B.h1, 64,  64, B.Wt + offs[7], B.Wt + offs[10], true,  B.h2, B, stream);
    run_gt_layer(B.h2, 64,  64, B.Wt + offs[8], B.Wt + offs[11], false, B.h1, B, stream);
    norm64_k<<<NN / 4, 256, 0, stream>>>(B.h1, B.mu);

    run_gt_layer(B.x,  128, 64, B.Wt + offs[12], B.Wt + offs[15], true,  B.h1, B, stream);
    run_gt_layer(B.h1, 64,  64, B.Wt + offs[13], B.Wt + offs[16], true,  B.h2, B, stream);
    run_gt_layer(B.h2, 64,  64, B.Wt + offs[14], B.Wt + offs[17], false, B.h1, B, stream);
    norm64_k<<<NN / 4, 256, 0, stream>>>(B.h1, B.lv);

    final_z_k<<<(NN * 64 + 255) / 256, 256, 0, stream>>>(B.mu, B.lv, out, ke0, ke1);
}

// Round 10
// 858.677 us; speedup vs baseline: 1.3350x; 1.0464x over previous
//
#include <hip/hip_runtime.h>
#include <stdint.h>
#include <math.h>

#define NN 50000          // nodes
#define NE 800000         // edges
#define NH 4              // heads

typedef __attribute__((ext_vector_type(8))) short short8;
typedef __attribute__((ext_vector_type(4))) float floatx4;

// ======================= bf16 helpers =======================
__device__ inline float bf2f(uint32_t u16)
{
    return __uint_as_float(u16 << 16);
}
__device__ inline uint16_t f2bf(float f)
{
    uint32_t u = __float_as_uint(f);
    uint32_t r = (u + 0x7fffu + ((u >> 16) & 1u)) >> 16;   // RNE
    return (uint16_t)r;
}
__device__ inline void unpk8(uint4 u, float* f)
{
    f[0] = bf2f(u.x & 0xffffu); f[1] = bf2f(u.x >> 16);
    f[2] = bf2f(u.y & 0xffffu); f[3] = bf2f(u.y >> 16);
    f[4] = bf2f(u.z & 0xffffu); f[5] = bf2f(u.z >> 16);
    f[6] = bf2f(u.w & 0xffffu); f[7] = bf2f(u.w >> 16);
}

// intra-wave LDS producer->consumer sync (single wave; no __syncthreads needed)
__device__ inline void wave_lds_sync()
{
    __builtin_amdgcn_wave_barrier();
    asm volatile("s_waitcnt lgkmcnt(0)" ::: "memory");
    __builtin_amdgcn_wave_barrier();
}

// ======================= JAX threefry2x32 (partitionable mode) =======================
__host__ __device__ inline void tf2x32(uint32_t k0, uint32_t k1,
                                       uint32_t x0, uint32_t x1,
                                       uint32_t& o0, uint32_t& o1)
{
    uint32_t ks2 = k0 ^ k1 ^ 0x1BD11BDAu;
    x0 += k0; x1 += k1;
#define TF_R(r) { x0 += x1; x1 = (x1 << (r)) | (x1 >> (32 - (r))); x1 ^= x0; }
    TF_R(13) TF_R(15) TF_R(26) TF_R(6)
    x0 += k1;  x1 += ks2 + 1u;
    TF_R(17) TF_R(29) TF_R(16) TF_R(24)
    x0 += ks2; x1 += k0 + 2u;
    TF_R(13) TF_R(15) TF_R(26) TF_R(6)
    x0 += k0;  x1 += k1 + 3u;
    TF_R(17) TF_R(29) TF_R(16) TF_R(24)
    x0 += k1;  x1 += ks2 + 4u;
    TF_R(13) TF_R(15) TF_R(26) TF_R(6)
    x0 += ks2; x1 += k0 + 5u;
#undef TF_R
    o0 = x0; o1 = x1;
}

__device__ inline uint32_t jax_bits32(uint32_t k0, uint32_t k1, uint32_t idx)
{
    uint32_t a, b;
    tf2x32(k0, k1, 0u, idx, a, b);
    return a ^ b;
}

__device__ inline float jax_u01(uint32_t bits)
{
    return __uint_as_float((bits >> 9) | 0x3f800000u) - 1.0f;
}

// XLA ErfInv32 (Giles 2012)
__device__ inline float erfinv_f(float x)
{
    float w = -log1pf(-x * x);
    float p;
    if (w < 5.0f) {
        w = w - 2.5f;
        p = 2.81022636e-08f;
        p = fmaf(p, w, 3.43273939e-07f);
        p = fmaf(p, w, -3.5233877e-06f);
        p = fmaf(p, w, -4.39150654e-06f);
        p = fmaf(p, w, 0.00021858087f);
        p = fmaf(p, w, -0.00125372503f);
        p = fmaf(p, w, -0.00417768164f);
        p = fmaf(p, w, 0.246640727f);
        p = fmaf(p, w, 1.50140941f);
    } else {
        w = sqrtf(w) - 3.0f;
        p = -0.000200214257f;
        p = fmaf(p, w, 0.000100950558f);
        p = fmaf(p, w, 0.00134934322f);
        p = fmaf(p, w, -0.00367342844f);
        p = fmaf(p, w, 0.00573950773f);
        p = fmaf(p, w, -0.0076224613f);
        p = fmaf(p, w, 0.00943887047f);
        p = fmaf(p, w, 1.00167406f);
        p = fmaf(p, w, 2.83297682f);
    }
    return p * x;
}

// ======================= utility kernels =======================
__global__ __launch_bounds__(256) void fill_u32_k(uint32_t* p, uint32_t v, int n)
{
    int i = blockIdx.x * blockDim.x + threadIdx.x;
    if (i < n) p[i] = v;
}

// ======================= weight convert: fp32 [B][K][C] -> bf16 Wt [B*C][K] =======================
struct WSeg { const float* src; int B, K, C, off; };
struct WSegs { WSeg s[18]; };

__global__ __launch_bounds__(256) void wconv_k(WSegs segs, uint16_t* __restrict__ Wt)
{
    WSeg sg = segs.s[blockIdx.y];
    int n = sg.B * sg.K * sg.C;
    int i = blockIdx.x * 256 + threadIdx.x;
    if (i >= n) return;
    int kc = sg.K * sg.C;
    int b = i / kc;
    int rr = i - b * kc;
    int k = rr / sg.C;
    int c = rr - k * sg.C;
    Wt[(size_t)sg.off + (size_t)(b * sg.C + c) * sg.K + k] = f2bf(sg.src[i]);
}

// ======================= CSR build (once per launch) =======================
__global__ __launch_bounds__(256) void hist_k(const int* __restrict__ dst, int* __restrict__ deg)
{
    int e = blockIdx.x * blockDim.x + threadIdx.x;
    if (e < NE) atomicAdd(&deg[dst[e]], 1);
}

#define SCAN_CHUNK 1024
#define SCAN_NBLK  ((NN + SCAN_CHUNK - 1) / SCAN_CHUNK)   // 49

__global__ __launch_bounds__(256) void scan1_k(const int* __restrict__ deg,
                                               int* __restrict__ rowptr,
                                               int* __restrict__ bsums)
{
    __shared__ int lds[256];
    int b = blockIdx.x, t = threadIdx.x;
    int base = b * SCAN_CHUNK + t * 4;
    int v0 = (base + 0 < NN) ? deg[base + 0] : 0;
    int v1 = (base + 1 < NN) ? deg[base + 1] : 0;
    int v2 = (base + 2 < NN) ? deg[base + 2] : 0;
    int v3 = (base + 3 < NN) ? deg[base + 3] : 0;
    int s = v0 + v1 + v2 + v3;
    lds[t] = s;
    __syncthreads();
    for (int off = 1; off < 256; off <<= 1) {
        int x = (t >= off) ? lds[t - off] : 0;
        __syncthreads();
        lds[t] += x;
        __syncthreads();
    }
    int excl = lds[t] - s;
    if (base + 0 < NN) rowptr[base + 0] = excl;
    if (base + 1 < NN) rowptr[base + 1] = excl + v0;
    if (base + 2 < NN) rowptr[base + 2] = excl + v0 + v1;
    if (base + 3 < NN) rowptr[base + 3] = excl + v0 + v1 + v2;
    if (t == 255) bsums[b] = lds[255];
}

__global__ void scan2_k(int* bsums)
{
    if (threadIdx.x == 0 && blockIdx.x == 0) {
        int run = 0;
        for (int i = 0; i < SCAN_NBLK; i++) { int t = bsums[i]; bsums[i] = run; run += t; }
    }
}

__global__ __launch_bounds__(256) void scan3_k(int* __restrict__ rowptr,
                                               const int* __restrict__ bsums,
                                               int* __restrict__ cursor)
{
    int i = blockIdx.x * blockDim.x + threadIdx.x;
    if (i < NN) {
        int r = rowptr[i] + bsums[i / SCAN_CHUNK];
        rowptr[i] = r;
        cursor[i] = r;
    }
    if (i == 0) rowptr[NN] = NE;
}

__global__ __launch_bounds__(256) void csr_scatter_k(const int* __restrict__ src,
                                                     const int* __restrict__ dst,
                                                     int* __restrict__ cursor,
                                                     int* __restrict__ esrc)
{
    int e = blockIdx.x * blockDim.x + threadIdx.x;
    if (e >= NE) return;
    int d = dst[e];
    int pos = atomicAdd(&cursor[d], 1);
    esrc[pos] = src[e];
}

// ======================= bf16 MFMA GEMM (optionally 2-way batched via blockIdx.y) =======================
struct GArg { const void* A; const uint16_t* W; uint16_t* C; };
struct GArgs2 { GArg a[2]; };

template<int K, int CH, bool AF32>
__global__ __launch_bounds__(256) void gemm_mfma_k(GArgs2 gs, int Ntot, int relu)
{
    constexpr int KP = K + 8;
    constexpr int KC = K / 8;
    constexpr int NT = CH / 16;
    extern __shared__ uint16_t smem[];
    uint16_t* As = smem;             // 64 x KP
    uint16_t* Ws = smem + 64 * KP;   // CH x KP

    const GArg g = gs.a[blockIdx.y];
    const uint16_t* W = g.W;
    uint16_t* C = g.C;

    const int tid = threadIdx.x;
    const int row0 = blockIdx.x * 64;
    const int w  = tid >> 6;
    const int l  = tid & 63;
    const int lm = l & 15;
    const int lq = l >> 4;

    // ---- stage A (64 rows x K) once; fp32 source converted in-flight ----
    for (int i = tid; i < 64 * KC; i += 256) {
        int r = i / KC, c = i - r * KC;
        int gr = row0 + r; if (gr >= NN) gr = NN - 1;
        if constexpr (AF32) {
            const float* Af = (const float*)g.A + (size_t)gr * K + c * 8;
            float4 f0 = *(const float4*)Af;
            float4 f1 = *(const float4*)(Af + 4);
            uint4 vv;
            vv.x = (uint32_t)f2bf(f0.x) | ((uint32_t)f2bf(f0.y) << 16);
            vv.y = (uint32_t)f2bf(f0.z) | ((uint32_t)f2bf(f0.w) << 16);
            vv.z = (uint32_t)f2bf(f1.x) | ((uint32_t)f2bf(f1.y) << 16);
            vv.w = (uint32_t)f2bf(f1.z) | ((uint32_t)f2bf(f1.w) << 16);
            *(uint4*)(As + r * KP + c * 8) = vv;
        } else {
            uint4 vv = *(const uint4*)((const uint16_t*)g.A + (size_t)gr * K + c * 8);
            *(uint4*)(As + r * KP + c * 8) = vv;
        }
    }

    const uint16_t* a_base = As + (16 * w + lm) * KP + lq * 8;
    const uint16_t* b_base = Ws + lm * KP + lq * 8;

    const int nchunks = Ntot / CH;
    for (int ch = 0; ch < nchunks; ch++) {
        __syncthreads();
        for (int i = tid; i < CH * KC; i += 256) {
            int r = i / KC, c = i - r * KC;
            uint4 vv = *(const uint4*)(W + (size_t)(ch * CH + r) * K + c * 8);
            *(uint4*)(Ws + r * KP + c * 8) = vv;
        }
        __syncthreads();

        floatx4 acc[NT];
#pragma unroll
        for (int nt = 0; nt < NT; nt++) acc[nt] = (floatx4){0.f, 0.f, 0.f, 0.f};

#pragma unroll
        for (int ks = 0; ks < K / 32; ks++) {
            short8 av = *(const short8*)(a_base + ks * 32);
#pragma unroll
            for (int nt = 0; nt < NT; nt++) {
                short8 bv = *(const short8*)(b_base + nt * 16 * KP + ks * 32);
                acc[nt] = __builtin_amdgcn_mfma_f32_16x16x32_bf16(av, bv, acc[nt], 0, 0, 0);
            }
        }

        const int rbase = row0 + 16 * w + lq * 4;
        const int cbase = ch * CH + lm;
#pragma unroll
        for (int nt = 0; nt < NT; nt++) {
#pragma unroll
            for (int r = 0; r < 4; r++) {
                int gr = rbase + r;
                if (gr < NN) {
                    float v = acc[nt][r];
                    if (relu) v = fmaxf(v, 0.0f);
                    C[(size_t)gr * Ntot + cbase + nt * 16] = f2bf(v);
                }
            }
        }
    }
}

// ======================= attention: 2 independent waves/block, 2-way batched =======================
// Per-batch qkv base pointer with runtime row stride `str`; row = [q(OD)|k(OD)|v(OD)] at base.
struct AArg { const uint16_t* qkv; uint16_t* agg; };
struct AArgs2 { AArg a[2]; };

template<int DH>
__global__ __launch_bounds__(128) void attn_dual_k(AArgs2 as,
                                                   const int* __restrict__ rowptr,
                                                   const int* __restrict__ esrc,
                                                   float scale, int str)
{
    constexpr int OD  = NH * DH;     // 128 / 64
    constexpr int QU  = DH / 8;      // uint4 loads per head slice (4 / 2)
    constexpr int CAP = 64;          // edges per chunk
    constexpr int NP  = CAP / 16;    // phase-1 passes (4)
    constexpr int FV  = OD / 16;     // dims per lane in phase 2 (8 / 4)

    __shared__ float s_sc[2][CAP][4];
    __shared__ int   s_sn[2][CAP];

    const uint16_t* qkv = as.a[blockIdx.y].qkv;
    uint16_t* agg       = as.a[blockIdx.y].agg;

    const int wv   = threadIdx.x >> 6;
    const int lane = threadIdx.x & 63;
    const int n    = blockIdx.x * 2 + wv;      // NN % 2 == 0
    const int h1   = lane & 3;
    const int e    = lane >> 2;
    const int g    = lane >> 4;
    const int dl   = lane & 15;
    const int h2   = dl >> 2;                  // head owning dims [dl*FV, dl*FV+FV)

    // q fragment (unpacked fp32) for phase-1 head
    float qf[DH];
    {
        const uint4* q4 = (const uint4*)(qkv + (size_t)n * str + h1 * DH);
#pragma unroll
        for (int i = 0; i < QU; i++) { uint4 u = q4[i]; unpk8(u, &qf[i * 8]); }
    }

    const int j0 = rowptr[n], j1 = rowptr[n + 1];

    float m = -INFINITY, l = 0.0f;
    float acc[FV];
#pragma unroll
    for (int i = 0; i < FV; i++) acc[i] = 0.0f;

    const int voff = 2 * OD + dl * FV;

    for (int c0 = j0; c0 < j1; c0 += CAP) {
        const int cn = min(j1 - c0, CAP);

        if (lane < cn) s_sn[wv][lane] = esrc[c0 + lane];
        wave_lds_sync();

        // ---- phase 1: scores ----
        float p[NP];
        float lm = -INFINITY;
#pragma unroll
        for (int t = 0; t < NP; t++) {
            const int j = e + 16 * t;
            float s = -INFINITY;
            if (j < cn) {
                const int sn = s_sn[wv][j];
                const uint4* kp = (const uint4*)(qkv + (size_t)sn * str + OD + h1 * DH);
                s = 0.0f;
#pragma unroll
                for (int i = 0; i < QU; i++) {
                    uint4 u = kp[i];
                    float kf[8];
                    unpk8(u, kf);
                    s = fmaf(qf[i * 8 + 0], kf[0], s); s = fmaf(qf[i * 8 + 1], kf[1], s);
                    s = fmaf(qf[i * 8 + 2], kf[2], s); s = fmaf(qf[i * 8 + 3], kf[3], s);
                    s = fmaf(qf[i * 8 + 4], kf[4], s); s = fmaf(qf[i * 8 + 5], kf[5], s);
                    s = fmaf(qf[i * 8 + 6], kf[6], s); s = fmaf(qf[i * 8 + 7], kf[7], s);
                }
                s *= scale;
            }
            p[t] = s;
            lm = fmaxf(lm, s);
        }
#pragma unroll
        for (int msk = 4; msk <= 32; msk <<= 1) lm = fmaxf(lm, __shfl_xor(lm, msk, 64));
        const float mn = fmaxf(m, lm);
        const float corr = expf(m - mn);   // first chunk: exp(-inf)=0 (acc already 0)
        m = mn;

        float ls = 0.0f;
#pragma unroll
        for (int t = 0; t < NP; t++) {
            const int j = e + 16 * t;
            float pe = 0.0f;
            if (j < cn) {
                pe = expf(p[t] - mn);
                s_sc[wv][j][h1] = pe;
            }
            ls += pe;
        }
#pragma unroll
        for (int msk = 4; msk <= 32; msk <<= 1) ls += __shfl_xor(ls, msk, 64);
        l = l * corr + ls;
        wave_lds_sync();

        // ---- phase 2: 4 edges x 16 dim-lanes per pass ----
        const float c2 = __shfl(corr, h2, 64);   // lane h2 has h1 == h2
#pragma unroll
        for (int i = 0; i < FV; i++) acc[i] *= c2;

        for (int jb = 0; jb < cn; jb += 4) {
            const int j = jb + g;
            if (j < cn) {
                const float alpha = s_sc[wv][j][h2];
                const int sn = s_sn[wv][j];
                if constexpr (FV == 8) {
                    uint4 u = *(const uint4*)(qkv + (size_t)sn * str + voff);
                    float vf[8];
                    unpk8(u, vf);
#pragma unroll
                    for (int i = 0; i < 8; i++) acc[i] = fmaf(alpha, vf[i], acc[i]);
                } else {
                    uint2 u = *(const uint2*)(qkv + (size_t)sn * str + voff);
                    acc[0] = fmaf(alpha, bf2f(u.x & 0xffffu), acc[0]);
                    acc[1] = fmaf(alpha, bf2f(u.x >> 16),     acc[1]);
                    acc[2] = fmaf(alpha, bf2f(u.y & 0xffffu), acc[2]);
                    acc[3] = fmaf(alpha, bf2f(u.y >> 16),     acc[3]);
                }
            }
        }
        wave_lds_sync();   // phase-2 LDS reads done before next chunk's s_sn writes
    }

    // ---- epilogue: reduce over g, normalize, write ----
    const float lh = __shfl(l, h2, 64);
    const float inv = (lh > 0.0f) ? 1.0f / lh : 0.0f;
#pragma unroll
    for (int i = 0; i < FV; i++) {
        acc[i] += __shfl_xor(acc[i], 16, 64);
        acc[i] += __shfl_xor(acc[i], 32, 64);
    }
    if (g == 0) {
        uint16_t* op = agg + (size_t)n * OD + dl * FV;
        uint32_t wword[FV / 2];
#pragma unroll
        for (int i = 0; i < FV / 2; i++)
            wword[i] = (uint32_t)f2bf(acc[2 * i] * inv) | ((uint32_t)f2bf(acc[2 * i + 1] * inv) << 16);
        if constexpr (FV == 8) {
            *(uint4*)op = make_uint4(wword[0], wword[1], wword[2], wword[3]);
        } else {
            *(uint2*)op = make_uint2(wword[0], wword[1]);
        }
    }
}

// ======================= norms / dropout / fused reparam tail =======================
__global__ __launch_bounds__(256) void norm_relu_drop_k(const uint16_t* __restrict__ in,
                                                        uint16_t* __restrict__ out,
                                                        uint32_t k0, uint32_t k1)
{
    int row = blockIdx.x * 4 + (threadIdx.x >> 6);
    int lane = threadIdx.x & 63;
    if (row >= NN) return;
    const uint16_t* r = in + (size_t)row * 128;
    float a = bf2f(r[lane]), b = bf2f(r[lane + 64]);
    float ss = fmaf(a, a, b * b);
#pragma unroll
    for (int m = 32; m > 0; m >>= 1) ss += __shfl_xor(ss, m, 64);
    float d = fmaxf(sqrtf(ss), 1e-12f);
    float ya = fmaxf(a / d, 0.0f);
    float yb = fmaxf(b / d, 0.0f);
    uint32_t ia = (uint32_t)row * 128u + (uint32_t)lane;
    float ua = jax_u01(jax_bits32(k0, k1, ia));
    float ub = jax_u01(jax_bits32(k0, k1, ia + 64u));
    uint16_t* o = out + (size_t)row * 128;
    o[lane]      = f2bf((ua < 0.5f) ? ya * 2.0f : 0.0f);
    o[lane + 64] = f2bf((ub < 0.5f) ? yb * 2.0f : 0.0f);
}

// fused: mu = l2norm(hmu), lv = l2norm(hlv), z = eps*(exp(lv)+1e-12)+mu
__global__ __launch_bounds__(256) void final_fused_k(const uint16_t* __restrict__ hmu,
                                                     const uint16_t* __restrict__ hlv,
                                                     float* __restrict__ out,
                                                     uint32_t k0, uint32_t k1)
{
    int row = blockIdx.x * 4 + (threadIdx.x >> 6);
    int lane = threadIdx.x & 63;
    if (row >= NN) return;
    const size_t idx = (size_t)row * 64 + lane;

    float a = bf2f(hmu[idx]);
    float sa = a * a;
#pragma unroll
    for (int m = 32; m > 0; m >>= 1) sa += __shfl_xor(sa, m, 64);
    float mu = a / fmaxf(sqrtf(sa), 1e-12f);

    float b = bf2f(hlv[idx]);
    float sb = b * b;
#pragma unroll
    for (int m = 32; m > 0; m >>= 1) sb += __shfl_xor(sb, m, 64);
    float lv = b / fmaxf(sqrtf(sb), 1e-12f);

    const float LO = -0.99999994f; // nextafter(-1, 0) in f32
    float u01 = jax_u01(jax_bits32(k0, k1, (uint32_t)idx));
    float u = fmaxf(LO, fmaf(u01, 2.0f, LO));
    float eps = 1.41421354f * erfinv_f(u);
    float stdv = expf(lv) + 1e-12f;
    out[idx] = fmaf(eps, stdv, mu);
}

// ======================= host side =======================
extern "C" void kernel_launch(void* const* d_in, const int* in_sizes, int n_in,
                              void* d_out, int out_size, void* d_ws, size_t ws_size,
                              hipStream_t stream)
{
    const float* feat    = (const float*)d_in[0];
    const int*   src     = (const int*)d_in[1];
    const int*   dst     = (const int*)d_in[2];
    const float* wqkv1_0 = (const float*)d_in[3];
    const float* wqkv1_r = (const float*)d_in[4];
    const float* wo1     = (const float*)d_in[5];
    const float* wqkv2_0 = (const float*)d_in[6];
    const float* wqkv2_r = (const float*)d_in[7];
    const float* wo2     = (const float*)d_in[8];
    const float* wqkv3_0 = (const float*)d_in[9];
    const float* wqkv3_r = (const float*)d_in[10];
    const float* wo3     = (const float*)d_in[11];
    float* out = (float*)d_out;

    char* wp = (char*)d_ws;
    auto alloc = [&](size_t bytes) { char* p = wp; wp += (bytes + 255) & ~(size_t)255; return p; };

    // ---- weight segments; gc2/gc3 qkv pairs adjacent for combined GEMMs ----
    WSegs segs;
    int offs[18];
    int acc_off = 0;
    auto seg = [&](int i, const float* p, int Bc, int Kc, int Cc) {
        segs.s[i].src = p; segs.s[i].B = Bc; segs.s[i].K = Kc; segs.s[i].C = Cc;
        segs.s[i].off = acc_off; offs[i] = acc_off; acc_off += Bc * Kc * Cc;
    };
    seg(0,  wqkv1_0,                 3, 256, 128);
    seg(1,  wqkv1_r,                 3, 128, 128);
    seg(2,  wqkv1_r + 3 * 128 * 128, 3, 128, 128);
    seg(3,  wo1,                     1, 128, 128);
    seg(4,  wo1 + 128 * 128,         1, 128, 128);
    seg(5,  wo1 + 2 * 128 * 128,     1, 128, 128);
    seg(6,  wqkv2_0,                 3, 128, 64);   // } contiguous 384 rows, K=128
    seg(7,  wqkv3_0,                 3, 128, 64);   // }
    seg(8,  wqkv2_r,                 3, 64, 64);
    seg(9,  wqkv3_r,                 3, 64, 64);
    seg(10, wqkv2_r + 3 * 64 * 64,   3, 64, 64);
    seg(11, wqkv3_r + 3 * 64 * 64,   3, 64, 64);
    seg(12, wo2,                     1, 64, 64);
    seg(13, wo2 + 64 * 64,           1, 64, 64);
    seg(14, wo2 + 2 * 64 * 64,       1, 64, 64);
    seg(15, wo3,                     1, 64, 64);
    seg(16, wo3 + 64 * 64,           1, 64, 64);
    seg(17, wo3 + 2 * 64 * 64,       1, 64, 64);

    uint16_t* Wt     = (uint16_t*)alloc((size_t)acc_off * 2);
    uint16_t* qkvL   = (uint16_t*)alloc((size_t)NN * 384 * 2);  // gc1 qkv / gc2+gc3 L1 combined
    uint16_t* agg128 = (uint16_t*)alloc((size_t)NN * 128 * 2);
    uint16_t* h1     = (uint16_t*)alloc((size_t)NN * 128 * 2);
    uint16_t* h2     = (uint16_t*)alloc((size_t)NN * 128 * 2);
    uint16_t* x      = (uint16_t*)alloc((size_t)NN * 128 * 2);
    uint16_t* qkv_mu = (uint16_t*)alloc((size_t)NN * 192 * 2);
    uint16_t* qkv_lv = (uint16_t*)alloc((size_t)NN * 192 * 2);
    uint16_t* agg_mu = (uint16_t*)alloc((size_t)NN * 64 * 2);
    uint16_t* agg_lv = (uint16_t*)alloc((size_t)NN * 64 * 2);
    uint16_t* hmu    = (uint16_t*)alloc((size_t)NN * 64 * 2);
    uint16_t* hlv    = (uint16_t*)alloc((size_t)NN * 64 * 2);
    uint16_t* hmu2   = (uint16_t*)alloc((size_t)NN * 64 * 2);
    uint16_t* hlv2   = (uint16_t*)alloc((size_t)NN * 64 * 2);
    int* rowptr = (int*)alloc((size_t)(NN + 1) * 4);
    int* cursor = (int*)alloc((size_t)NN * 4);
    int* bsums  = (int*)alloc((size_t)SCAN_NBLK * 4);
    int* esrc   = (int*)alloc((size_t)NE * 4);

    wconv_k<<<dim3(384, 18), 256, 0, stream>>>(segs, Wt);

    fill_u32_k<<<(NN + 255) / 256, 256, 0, stream>>>((uint32_t*)cursor, 0u, NN);
    hist_k<<<(NE + 255) / 256, 256, 0, stream>>>(dst, cursor);
    scan1_k<<<SCAN_NBLK, 256, 0, stream>>>(cursor, rowptr, bsums);
    scan2_k<<<1, 64, 0, stream>>>(bsums);
    scan3_k<<<(NN + 255) / 256, 256, 0, stream>>>(rowptr, bsums, cursor);
    csr_scatter_k<<<(NE + 255) / 256, 256, 0, stream>>>(src, dst, cursor, esrc);

    uint32_t kd0, kd1, ke0, ke1;
    tf2x32(0u, 42u, 0u, 0u, kd0, kd1);
    tf2x32(0u, 42u, 0u, 1u, ke0, ke1);

    const int GX = (NN + 63) / 64;   // 782
    const float sc32 = 1.0f / sqrtf(32.0f);
    const float sc16 = 0.25f;

    auto g1 = [&](GArg a) { GArgs2 g; g.a[0] = a; g.a[1] = a; return g; };
    auto g2 = [&](GArg a0, GArg a1) { GArgs2 g; g.a[0] = a0; g.a[1] = a1; return g; };
    auto a1 = [&](AArg a) { AArgs2 r; r.a[0] = a; r.a[1] = a; return r; };
    auto a2 = [&](AArg a0, AArg b0) { AArgs2 r; r.a[0] = a0; r.a[1] = b0; return r; };

    // LDS sizes
    const size_t L256_32  = (size_t)(64 + 32)  * (256 + 8) * 2;   // 50688
    const size_t L128_128 = (size_t)(64 + 128) * (128 + 8) * 2;   // 52224
    const size_t L64_192  = (size_t)(64 + 192) * (64 + 8) * 2;    // 36864
    const size_t L64_64   = (size_t)(64 + 64)  * (64 + 8) * 2;    // 18432

    // ================= gc1 (od=128) =================
    gemm_mfma_k<256, 32, true><<<dim3(GX, 1), 256, L256_32, stream>>>(
        g1({feat, Wt + offs[0], qkvL}), 384, 0);
    attn_dual_k<32><<<dim3(NN / 2, 1), 128, 0, stream>>>(a1({qkvL, agg128}), rowptr, esrc, sc32, 384);
    gemm_mfma_k<128, 128, false><<<dim3(GX, 1), 256, L128_128, stream>>>(
        g1({agg128, Wt + offs[3], h1}), 128, 1);

    gemm_mfma_k<128, 128, false><<<dim3(GX, 1), 256, L128_128, stream>>>(
        g1({h1, Wt + offs[1], qkvL}), 384, 0);
    attn_dual_k<32><<<dim3(NN / 2, 1), 128, 0, stream>>>(a1({qkvL, agg128}), rowptr, esrc, sc32, 384);
    gemm_mfma_k<128, 128, false><<<dim3(GX, 1), 256, L128_128, stream>>>(
        g1({agg128, Wt + offs[4], h2}), 128, 1);

    gemm_mfma_k<128, 128, false><<<dim3(GX, 1), 256, L128_128, stream>>>(
        g1({h2, Wt + offs[2], qkvL}), 384, 0);
    attn_dual_k<32><<<dim3(NN / 2, 1), 128, 0, stream>>>(a1({qkvL, agg128}), rowptr, esrc, sc32, 384);
    gemm_mfma_k<128, 128, false><<<dim3(GX, 1), 256, L128_128, stream>>>(
        g1({agg128, Wt + offs[5], h1}), 128, 0);

    norm_relu_drop_k<<<NN / 4, 256, 0, stream>>>(h1, x, kd0, kd1);

    // ================= gc2 + gc3 batched (od=64) =================
    // L1: combined qkv GEMM (weights gc2|gc3 contiguous -> Ntot=384), one buffer
    gemm_mfma_k<128, 128, false><<<dim3(GX, 1), 256, L128_128, stream>>>(
        g1({x, Wt + offs[6], qkvL}), 384, 0);
    attn_dual_k<16><<<dim3(NN / 2, 2), 128, 0, stream>>>(
        a2({qkvL, agg_mu}, {qkvL + 192, agg_lv}), rowptr, esrc, sc16, 384);
    gemm_mfma_k<64, 64, false><<<dim3(GX, 2), 256, L64_64, stream>>>(
        g2({agg_mu, Wt + offs[12], hmu}, {agg_lv, Wt + offs[15], hlv}), 64, 1);

    // L2
    gemm_mfma_k<64, 192, false><<<dim3(GX, 2), 256, L64_192, stream>>>(
        g2({hmu, Wt + offs[8], qkv_mu}, {hlv, Wt + offs[9], qkv_lv}), 192, 0);
    attn_dual_k<16><<<dim3(NN / 2, 2), 128, 0, stream>>>(
        a2({qkv_mu, agg_mu}, {qkv_lv, agg_lv}), rowptr, esrc, sc16, 192);
    gemm_mfma_k<64, 64, false><<<dim3(GX, 2), 256, L64_64, stream>>>(
        g2({agg_mu, Wt + offs[13], hmu2}, {agg_lv, Wt + offs[16], hlv2}), 64, 1);

    // L3
    gemm_mfma_k<64, 192, false><<<dim3(GX, 2), 256, L64_192, stream>>>(
        g2({hmu2, Wt + offs[10], qkv_mu}, {hlv2, Wt + offs[11], qkv_lv}), 192, 0);
    attn_dual_k<16><<<dim3(NN / 2, 2), 128, 0, stream>>>(
        a2({qkv_mu, agg_mu}, {qkv_lv, agg_lv}), rowptr, esrc, sc16, 192);
    gemm_mfma_k<64, 64, false><<<dim3(GX, 2), 256, L64_64, stream>>>(
        g2({agg_mu, Wt + offs[14], hmu}, {agg_lv, Wt + offs[17], hlv}), 64, 0);

    // ================= fused l2norm(mu), l2norm(lv), reparameterize =================
    final_fused_k<<<NN / 4, 256, 0, stream>>>(hmu, hlv, out, ke0, ke1);
}